// Round 1
// baseline (5804.663 us; speedup 1.0000x reference)
//
#include <hip/hip_runtime.h>

typedef float f32x4 __attribute__((ext_vector_type(4)));
typedef short short8 __attribute__((ext_vector_type(8)));

#define NWG_S 8  // serial-chain worker workgroups

__device__ __forceinline__ unsigned short f2bf(float f) {
  unsigned int u = __float_as_uint(f);
  u += 0x7fffu + ((u >> 16) & 1u);
  return (unsigned short)(u >> 16);
}

// ---------------- workspace layout (bytes) ----------------
// 0       : w2t       bf16[128][576]  transposed conv2 weights (147456)
// 147456  : feats_sum f32 [128][128]  (65536)   zeroed each launch
// 212992  : ev        f32 [896]       (3584)
// 216576  : base      f32 [128][400]  (204800)
// 421376  : a_buf     f32 [512]       (2048)
// 423424  : S         f32 [128]       (512)     zeroed each launch
// 423936  : bar       int [2]                   zeroed each launch
// 458752  : c1        bf16[FCHUNK][128][128][64] (FCHUNK*2 MiB)

// ================= prep: zero accumulators, transpose conv2_w, fce branch ==
__global__ __launch_bounds__(256) void prep_k(
    const float* __restrict__ enc, const float* __restrict__ fce_w,
    const float* __restrict__ fce_b, const float* __restrict__ conv2_w,
    unsigned short* __restrict__ w2t, float* __restrict__ ev,
    float* __restrict__ feats_sum, float* __restrict__ S,
    int* __restrict__ bar) {
  int b = blockIdx.x, t = threadIdx.x;
  if (b < 48) {
    for (int i = b * 256 + t; i < 16514; i += 48 * 256) {
      if (i < 16384) feats_sum[i] = 0.f;
      else if (i < 16512) S[i - 16384] = 0.f;
      else bar[i - 16512] = 0;
    }
    for (int i = b * 256 + t; i < 73728; i += 48 * 256) {
      int oc = i / 576, k = i - oc * 576;
      int p = k >> 6, ic = k & 63;
      int ky = p / 3, kx = p - ky * 3;
      w2t[i] = f2bf(conv2_w[((oc * 64 + ic) * 3 + ky) * 3 + kx]);
    }
  } else {
    // ev[n*64+o] = relu(enc[n,:] . fce_w[o,:] + fce_b[o]); 16 blocks x 56 outs
    if (t < 224) {
      int o_l = t >> 2, part = t & 3;
      int o_glob = (b - 48) * 56 + o_l;
      int n = o_glob >> 6, o = o_glob & 63;
      const f32x4* e4 = (const f32x4*)(enc + n * 2048);
      const f32x4* w4 = (const f32x4*)(fce_w + o * 2048);
      float s = 0.f;
      for (int d = part * 128; d < part * 128 + 128; ++d) {
        f32x4 a = e4[d], w = w4[d];
        s += a.x * w.x + a.y * w.y + a.z * w.z + a.w * w.w;
      }
      s += __shfl_xor(s, 1);
      s += __shfl_xor(s, 2);
      if (part == 0) ev[o_glob] = fmaxf(s + fce_b[o], 0.f);
    }
  }
}

// ================= conv1: f32 in -> relu -> bf16 NHWC out ==================
__global__ __launch_bounds__(256) void conv1_k(
    const float* __restrict__ vid, const float* __restrict__ cw,
    const float* __restrict__ cb, unsigned short* __restrict__ c1, int fbase) {
  int f_local = blockIdx.x >> 6;
  int pix = (blockIdx.x & 63) * 256 + threadIdx.x;  // 0..16383
  int oy = pix >> 7, ox = pix & 127;
  int f = fbase + f_local;
  float inv[27];
#pragma unroll
  for (int c = 0; c < 3; ++c)
#pragma unroll
    for (int ky = 0; ky < 3; ++ky)
#pragma unroll
      for (int kx = 0; kx < 3; ++kx) {
        int iy = 2 * oy - 1 + ky, ix = 2 * ox - 1 + kx;
        bool ok = (iy >= 0 && iy < 256 && ix >= 0 && ix < 256);
        inv[c * 9 + ky * 3 + kx] = ok ? vid[((f * 3 + c) * 256 + iy) * 256 + ix] : 0.f;
      }
  long obase = (long)((f_local * 128 + oy) * 128 + ox) * 64;
  for (int g = 0; g < 8; ++g) {  // oc in groups of 8, weights via uniform (scalar) loads
    unsigned short pack[8];
#pragma unroll
    for (int j = 0; j < 8; ++j) {
      int oc = g * 8 + j;
      float s = cb[oc];
#pragma unroll
      for (int i = 0; i < 27; ++i) s += cw[oc * 27 + i] * inv[i];
      pack[j] = f2bf(fmaxf(s, 0.f));
    }
    *(uint4*)&c1[obase + g * 8] = *(const uint4*)pack;
  }
}

// ============ conv2: MFMA implicit GEMM + relu + spatial-mean ==============
// M-tile 128 pixels/WG, N=128 oc, K=576 in 18 steps of 32.
__global__ __launch_bounds__(256) void conv2_k(
    const unsigned short* __restrict__ c1, const unsigned short* __restrict__ w2t,
    const float* __restrict__ c2b, float* __restrict__ feats_sum, int fbase) {
  __shared__ unsigned short As[128 * 40];  // [row][k] pad 32->40 (bank spread)
  __shared__ unsigned short Bs[128 * 40];  // [oc][k]  (B^T layout)
  __shared__ float fred[128];
  int t = threadIdx.x;
  int f_local = blockIdx.x >> 5, mb = blockIdx.x & 31;
  int wave = t >> 6, lane = t & 63;

  f32x4 acc0[8], acc1[8];
#pragma unroll
  for (int n = 0; n < 8; ++n) {
    acc0[n] = (f32x4){0.f, 0.f, 0.f, 0.f};
    acc1[n] = (f32x4){0.f, 0.f, 0.f, 0.f};
  }

  int r = t >> 1, seg = t & 1;          // staging: 2 threads/row, 16 bf16 each
  int m = mb * 128 + r;
  int oy = m >> 6, ox = m & 63;
  const int aoff = r * 40 + seg * 16;

  for (int kk = 0; kk < 18; ++kk) {
    int p = kk >> 1, ic0 = (kk & 1) * 32;
    int ky = p / 3, kx = p - ky * 3;
    int iy = 2 * oy - 1 + ky, ix = 2 * ox - 1 + kx;
    if (iy >= 0 && iy < 128 && ix >= 0 && ix < 128) {
      const unsigned short* src =
          &c1[(long)((f_local * 128 + iy) * 128 + ix) * 64 + ic0 + seg * 16];
      *(uint4*)&As[aoff] = *(const uint4*)&src[0];
      *(uint4*)&As[aoff + 8] = *(const uint4*)&src[8];
    } else {
      *(uint4*)&As[aoff] = make_uint4(0u, 0u, 0u, 0u);
      *(uint4*)&As[aoff + 8] = make_uint4(0u, 0u, 0u, 0u);
    }
    {
      const unsigned short* src = &w2t[r * 576 + p * 64 + ic0 + seg * 16];
      *(uint4*)&Bs[aoff] = *(const uint4*)&src[0];
      *(uint4*)&Bs[aoff + 8] = *(const uint4*)&src[8];
    }
    __syncthreads();
    short8 av0 = *(const short8*)&As[(wave * 32 + (lane & 15)) * 40 + (lane >> 4) * 8];
    short8 av1 = *(const short8*)&As[(wave * 32 + 16 + (lane & 15)) * 40 + (lane >> 4) * 8];
#pragma unroll
    for (int n = 0; n < 8; ++n) {
      short8 bv = *(const short8*)&Bs[(n * 16 + (lane & 15)) * 40 + (lane >> 4) * 8];
      acc0[n] = __builtin_amdgcn_mfma_f32_16x16x32_bf16(av0, bv, acc0[n], 0, 0, 0);
      acc1[n] = __builtin_amdgcn_mfma_f32_16x16x32_bf16(av1, bv, acc1[n], 0, 0, 0);
    }
    __syncthreads();
  }

  // epilogue: bias + relu + sum over this WG's 128 pixels, then one atomic/oc
  if (t < 128) fred[t] = 0.f;
  __syncthreads();
  int f = fbase + f_local;
  int colLane = lane & 15;
#pragma unroll
  for (int n = 0; n < 8; ++n) {
    float bias = c2b[n * 16 + colLane];
    float s = 0.f;
#pragma unroll
    for (int q = 0; q < 4; ++q)
      s += fmaxf(acc0[n][q] + bias, 0.f) + fmaxf(acc1[n][q] + bias, 0.f);
    s += __shfl_xor(s, 16);
    s += __shfl_xor(s, 32);
    if (lane < 16) atomicAdd(&fred[n * 16 + colLane], s);
  }
  __syncthreads();
  if (t < 128) atomicAdd(&feats_sum[f * 128 + t], fred[t]);
}

// ====== base[t][c] = feats_t.Wf + ev.We + fc_b (time-independent part) =====
__global__ __launch_bounds__(256) void base_k(
    const float* __restrict__ feats_sum, const float* __restrict__ ev,
    const float* __restrict__ fc_w, const float* __restrict__ fc_b,
    float* __restrict__ base) {
  __shared__ float xv[1024];
  int tfr = blockIdx.x, t = threadIdx.x;
  for (int i = t; i < 1024; i += 256)
    xv[i] = (i < 128) ? feats_sum[tfr * 128 + i] * (1.f / 4096.f) : ev[i - 128];
  __syncthreads();
  for (int c = t; c < 400; c += 256) {
    const float* wr = fc_w + c * 1536;
    float s = fc_b[c];
    for (int k = 0; k < 1024; k += 4) {
      f32x4 w4 = *(const f32x4*)&wr[k];
      s += w4.x * xv[k] + w4.y * xv[k + 1] + w4.z * xv[k + 2] + w4.w * xv[k + 3];
    }
    base[tfr * 400 + c] = s;
  }
}

// ================= device-wide barrier for the serial chain ================
__device__ __forceinline__ void gbar(int* __restrict__ bar) {
  __threadfence();
  __syncthreads();
  if (threadIdx.x == 0) {
    int g0 = __hip_atomic_load(&bar[1], __ATOMIC_RELAXED, __HIP_MEMORY_SCOPE_AGENT);
    int v = __hip_atomic_fetch_add(&bar[0], 1, __ATOMIC_ACQ_REL, __HIP_MEMORY_SCOPE_AGENT);
    if (v == NWG_S - 1) {
      __hip_atomic_store(&bar[0], 0, __ATOMIC_RELAXED, __HIP_MEMORY_SCOPE_AGENT);
      __hip_atomic_store(&bar[1], g0 + 1, __ATOMIC_RELEASE, __HIP_MEMORY_SCOPE_AGENT);
    } else {
      while (__hip_atomic_load(&bar[1], __ATOMIC_ACQUIRE, __HIP_MEMORY_SCOPE_AGENT) == g0)
        __builtin_amdgcn_s_sleep(2);
    }
  }
  __syncthreads();
  __threadfence();
}

// ============ serial chain: 128 steps, softmax-normalization deferred ======
// e_t = exp(base_t + Wa @ relu( (fca_w @ e_{t-1})/S_{t-1} + fca_b ))
// d_out holds unnormalized e; norm_k divides by S afterwards.
__global__ __launch_bounds__(256) void serial_k(
    const float* __restrict__ fca_w, const float* __restrict__ fca_b,
    const float* __restrict__ fc_w, const float* __restrict__ action,
    const float* __restrict__ base, float* __restrict__ a_buf,
    float* __restrict__ S, float* __restrict__ e_out, int* __restrict__ bar) {
  if (blockIdx.x & 7) return;     // workers at blockIdx 0,8,..,56 (XCD-spread trick)
  int g = blockIdx.x >> 3;        // 0..7
  int t = threadIdx.x;
  __shared__ float sh_e[400];
  __shared__ float sh_a[512];
  __shared__ float sred[64];

  for (int step = 0; step < 128; ++step) {
    const float* eprev = step ? (e_out + (step - 1) * 400) : action;
    for (int i = t; i < 400; i += 256) sh_e[i] = eprev[i];
    __syncthreads();
    float Sprev = step ? S[step - 1] : 1.f;
    {  // phase A: 64 rows of a per WG, 4 lanes/row
      int row = g * 64 + (t >> 2);
      const float* wr = fca_w + row * 400;
      float s = 0.f;
      for (int j = t & 3; j < 400; j += 4) s += wr[j] * sh_e[j];
      s += __shfl_xor(s, 1);
      s += __shfl_xor(s, 2);
      if ((t & 3) == 0) a_buf[row] = fmaxf(s / Sprev + fca_b[row], 0.f);
    }
    gbar(bar);
    for (int i = t; i < 512; i += 256) sh_a[i] = a_buf[i];
    __syncthreads();
    if (t < 200) {  // phase B: 50 logit rows per WG, 4 lanes/row
      int row = g * 50 + (t >> 2);
      const float* wr = fc_w + row * 1536 + 1024;
      float s = 0.f;
      for (int j = t & 3; j < 512; j += 4) s += wr[j] * sh_a[j];
      s += __shfl_xor(s, 1);
      s += __shfl_xor(s, 2);
      if ((t & 3) == 0) {
        float e = __expf(s + base[step * 400 + row]);
        e_out[step * 400 + row] = e;
        sred[t >> 2] = e;
      }
    }
    __syncthreads();
    if (t == 0) {
      float tot = 0.f;
      for (int i = 0; i < 50; ++i) tot += sred[i];
      atomicAdd(&S[step], tot);
    }
    gbar(bar);
  }
}

// ================= final softmax normalization =============================
__global__ __launch_bounds__(256) void norm_k(float* __restrict__ out,
                                              const float* __restrict__ S) {
  int i = blockIdx.x * 256 + threadIdx.x;
  if (i < 51200) out[i] = out[i] / S[i / 400];
}

extern "C" void kernel_launch(void* const* d_in, const int* in_sizes, int n_in,
                              void* d_out, int out_size, void* d_ws, size_t ws_size,
                              hipStream_t stream) {
  (void)in_sizes; (void)n_in; (void)out_size;
  const float* enc    = (const float*)d_in[0];
  const float* vid    = (const float*)d_in[1];
  const float* action = (const float*)d_in[2];
  const float* c1w    = (const float*)d_in[3];
  const float* c1b    = (const float*)d_in[4];
  const float* c2w    = (const float*)d_in[5];
  const float* c2b    = (const float*)d_in[6];
  const float* fce_w  = (const float*)d_in[7];
  const float* fce_b  = (const float*)d_in[8];
  const float* fca_w  = (const float*)d_in[9];
  const float* fca_b  = (const float*)d_in[10];
  const float* fc_w   = (const float*)d_in[11];
  const float* fc_b   = (const float*)d_in[12];
  // d_in[13..16] (wih/whh/bih/bhh): dead code — LSTM state never reaches the output.
  float* out = (float*)d_out;
  char* ws = (char*)d_ws;
  unsigned short* w2t = (unsigned short*)(ws + 0);
  float* feats_sum    = (float*)(ws + 147456);
  float* ev           = (float*)(ws + 212992);
  float* base         = (float*)(ws + 216576);
  float* a_buf        = (float*)(ws + 421376);
  float* S            = (float*)(ws + 423424);
  int*   bar          = (int*)(ws + 423936);
  unsigned short* c1  = (unsigned short*)(ws + 458752);

  // choose frame-chunk size to fit the workspace (c1 = fchunk * 2 MiB)
  int fchunk = 32;
  while (fchunk > 1 && 458752ull + (unsigned long long)fchunk * 2097152ull > ws_size)
    fchunk >>= 1;

  hipLaunchKernelGGL(prep_k, dim3(64), dim3(256), 0, stream,
                     enc, fce_w, fce_b, c2w, w2t, ev, feats_sum, S, bar);
  for (int fb = 0; fb < 128; fb += fchunk) {
    hipLaunchKernelGGL(conv1_k, dim3(fchunk * 64), dim3(256), 0, stream,
                       vid, c1w, c1b, c1, fb);
    hipLaunchKernelGGL(conv2_k, dim3(fchunk * 32), dim3(256), 0, stream,
                       c1, w2t, c2b, feats_sum, fb);
  }
  hipLaunchKernelGGL(base_k, dim3(128), dim3(256), 0, stream,
                     feats_sum, ev, fc_w, fc_b, base);
  hipLaunchKernelGGL(serial_k, dim3(57), dim3(256), 0, stream,
                     fca_w, fca_b, fc_w, action, base, a_buf, S, out, bar);
  hipLaunchKernelGGL(norm_k, dim3(200), dim3(256), 0, stream, out, S);
}

// Round 2
// 2330.162 us; speedup vs baseline: 2.4911x; 2.4911x over previous
//
#include <hip/hip_runtime.h>

typedef float f32x4 __attribute__((ext_vector_type(4)));
typedef short short8 __attribute__((ext_vector_type(8)));

#define NWG_S 16   // serial-chain worker workgroups
#define AR 32      // fca rows per WG (512/16)
#define BR 25      // fc rows per WG (400/16)

__device__ __forceinline__ unsigned short f2bf(float f) {
  unsigned int u = __float_as_uint(f);
  u += 0x7fffu + ((u >> 16) & 1u);
  return (unsigned short)(u >> 16);
}

// ---------------- workspace layout (bytes) ----------------
// 0       : w2t       bf16[128][576]  transposed conv2 weights (147456)
// 147456  : feats_sum f32 [128][128]  (65536)   zeroed each launch
// 212992  : ev        f32 [896]       (3584)
// 216576  : base      f32 [128][400]  (204800)
// 421376  : a_buf     f32 [512]       (2048)
// 423424  : Sp        f32 [128][16]   (8192)    partial softmax sums (no zero needed)
// 431616  : bar       int [2]                   zeroed each launch
// 458752  : c1        bf16[FCHUNK][128][128][64] (FCHUNK*2 MiB)

// ================= prep: zero accumulators, transpose conv2_w, fce branch ==
__global__ __launch_bounds__(256) void prep_k(
    const float* __restrict__ enc, const float* __restrict__ fce_w,
    const float* __restrict__ fce_b, const float* __restrict__ conv2_w,
    unsigned short* __restrict__ w2t, float* __restrict__ ev,
    float* __restrict__ feats_sum, int* __restrict__ bar) {
  int b = blockIdx.x, t = threadIdx.x;
  if (b < 48) {
    for (int i = b * 256 + t; i < 16386; i += 48 * 256) {
      if (i < 16384) feats_sum[i] = 0.f;
      else bar[i - 16384] = 0;
    }
    for (int i = b * 256 + t; i < 73728; i += 48 * 256) {
      int oc = i / 576, k = i - oc * 576;
      int p = k >> 6, ic = k & 63;
      int ky = p / 3, kx = p - ky * 3;
      w2t[i] = f2bf(conv2_w[((oc * 64 + ic) * 3 + ky) * 3 + kx]);
    }
  } else {
    // ev[n*64+o] = relu(enc[n,:] . fce_w[o,:] + fce_b[o]); 16 blocks x 56 outs
    if (t < 224) {
      int o_l = t >> 2, part = t & 3;
      int o_glob = (b - 48) * 56 + o_l;
      int n = o_glob >> 6, o = o_glob & 63;
      const f32x4* e4 = (const f32x4*)(enc + n * 2048);
      const f32x4* w4 = (const f32x4*)(fce_w + o * 2048);
      float s = 0.f;
      for (int d = part * 128; d < part * 128 + 128; ++d) {
        f32x4 a = e4[d], w = w4[d];
        s += a.x * w.x + a.y * w.y + a.z * w.z + a.w * w.w;
      }
      s += __shfl_xor(s, 1);
      s += __shfl_xor(s, 2);
      if (part == 0) ev[o_glob] = fmaxf(s + fce_b[o], 0.f);
    }
  }
}

// ================= conv1: f32 in -> relu -> bf16 NHWC out ==================
__global__ __launch_bounds__(256) void conv1_k(
    const float* __restrict__ vid, const float* __restrict__ cw,
    const float* __restrict__ cb, unsigned short* __restrict__ c1, int fbase) {
  int f_local = blockIdx.x >> 6;
  int pix = (blockIdx.x & 63) * 256 + threadIdx.x;  // 0..16383
  int oy = pix >> 7, ox = pix & 127;
  int f = fbase + f_local;
  float inv[27];
#pragma unroll
  for (int c = 0; c < 3; ++c)
#pragma unroll
    for (int ky = 0; ky < 3; ++ky)
#pragma unroll
      for (int kx = 0; kx < 3; ++kx) {
        int iy = 2 * oy - 1 + ky, ix = 2 * ox - 1 + kx;
        bool ok = (iy >= 0 && iy < 256 && ix >= 0 && ix < 256);
        inv[c * 9 + ky * 3 + kx] = ok ? vid[((f * 3 + c) * 256 + iy) * 256 + ix] : 0.f;
      }
  long obase = (long)((f_local * 128 + oy) * 128 + ox) * 64;
  for (int g = 0; g < 8; ++g) {  // oc in groups of 8, weights via uniform (scalar) loads
    unsigned short pack[8];
#pragma unroll
    for (int j = 0; j < 8; ++j) {
      int oc = g * 8 + j;
      float s = cb[oc];
#pragma unroll
      for (int i = 0; i < 27; ++i) s += cw[oc * 27 + i] * inv[i];
      pack[j] = f2bf(fmaxf(s, 0.f));
    }
    *(uint4*)&c1[obase + g * 8] = *(const uint4*)pack;
  }
}

// ============ conv2: MFMA implicit GEMM + relu + spatial-mean ==============
// M-tile 128 pixels/WG, N=128 oc, K=576 in 18 steps of 32.
__global__ __launch_bounds__(256) void conv2_k(
    const unsigned short* __restrict__ c1, const unsigned short* __restrict__ w2t,
    const float* __restrict__ c2b, float* __restrict__ feats_sum, int fbase) {
  __shared__ unsigned short As[128 * 40];  // [row][k] pad 32->40 (bank spread)
  __shared__ unsigned short Bs[128 * 40];  // [oc][k]  (B^T layout)
  __shared__ float fred[128];
  int t = threadIdx.x;
  int f_local = blockIdx.x >> 5, mb = blockIdx.x & 31;
  int wave = t >> 6, lane = t & 63;

  f32x4 acc0[8], acc1[8];
#pragma unroll
  for (int n = 0; n < 8; ++n) {
    acc0[n] = (f32x4){0.f, 0.f, 0.f, 0.f};
    acc1[n] = (f32x4){0.f, 0.f, 0.f, 0.f};
  }

  int r = t >> 1, seg = t & 1;          // staging: 2 threads/row, 16 bf16 each
  int m = mb * 128 + r;
  int oy = m >> 6, ox = m & 63;
  const int aoff = r * 40 + seg * 16;

  for (int kk = 0; kk < 18; ++kk) {
    int p = kk >> 1, ic0 = (kk & 1) * 32;
    int ky = p / 3, kx = p - ky * 3;
    int iy = 2 * oy - 1 + ky, ix = 2 * ox - 1 + kx;
    if (iy >= 0 && iy < 128 && ix >= 0 && ix < 128) {
      const unsigned short* src =
          &c1[(long)((f_local * 128 + iy) * 128 + ix) * 64 + ic0 + seg * 16];
      *(uint4*)&As[aoff] = *(const uint4*)&src[0];
      *(uint4*)&As[aoff + 8] = *(const uint4*)&src[8];
    } else {
      *(uint4*)&As[aoff] = make_uint4(0u, 0u, 0u, 0u);
      *(uint4*)&As[aoff + 8] = make_uint4(0u, 0u, 0u, 0u);
    }
    {
      const unsigned short* src = &w2t[r * 576 + p * 64 + ic0 + seg * 16];
      *(uint4*)&Bs[aoff] = *(const uint4*)&src[0];
      *(uint4*)&Bs[aoff + 8] = *(const uint4*)&src[8];
    }
    __syncthreads();
    short8 av0 = *(const short8*)&As[(wave * 32 + (lane & 15)) * 40 + (lane >> 4) * 8];
    short8 av1 = *(const short8*)&As[(wave * 32 + 16 + (lane & 15)) * 40 + (lane >> 4) * 8];
#pragma unroll
    for (int n = 0; n < 8; ++n) {
      short8 bv = *(const short8*)&Bs[(n * 16 + (lane & 15)) * 40 + (lane >> 4) * 8];
      acc0[n] = __builtin_amdgcn_mfma_f32_16x16x32_bf16(av0, bv, acc0[n], 0, 0, 0);
      acc1[n] = __builtin_amdgcn_mfma_f32_16x16x32_bf16(av1, bv, acc1[n], 0, 0, 0);
    }
    __syncthreads();
  }

  // epilogue: bias + relu + sum over this WG's 128 pixels, then one atomic/oc
  if (t < 128) fred[t] = 0.f;
  __syncthreads();
  int f = fbase + f_local;
  int colLane = lane & 15;
#pragma unroll
  for (int n = 0; n < 8; ++n) {
    float bias = c2b[n * 16 + colLane];
    float s = 0.f;
#pragma unroll
    for (int q = 0; q < 4; ++q)
      s += fmaxf(acc0[n][q] + bias, 0.f) + fmaxf(acc1[n][q] + bias, 0.f);
    s += __shfl_xor(s, 16);
    s += __shfl_xor(s, 32);
    if (lane < 16) atomicAdd(&fred[n * 16 + colLane], s);
  }
  __syncthreads();
  if (t < 128) atomicAdd(&feats_sum[f * 128 + t], fred[t]);
}

// ====== base[t][c] = feats_t.Wf + ev.We + fc_b (time-independent part) =====
__global__ __launch_bounds__(256) void base_k(
    const float* __restrict__ feats_sum, const float* __restrict__ ev,
    const float* __restrict__ fc_w, const float* __restrict__ fc_b,
    float* __restrict__ base) {
  __shared__ float xv[1024];
  int tfr = blockIdx.x, t = threadIdx.x;
  for (int i = t; i < 1024; i += 256)
    xv[i] = (i < 128) ? feats_sum[tfr * 128 + i] * (1.f / 4096.f) : ev[i - 128];
  __syncthreads();
  for (int c = t; c < 400; c += 256) {
    const float* wr = fc_w + c * 1536;
    float s = fc_b[c];
    for (int k = 0; k < 1024; k += 4) {
      f32x4 w4 = *(const f32x4*)&wr[k];
      s += w4.x * xv[k] + w4.y * xv[k + 1] + w4.z * xv[k + 2] + w4.w * xv[k + 3];
    }
    base[tfr * 400 + c] = s;
  }
}

// ================= device-wide barrier for the serial chain ================
// Lean: release-fence once, relaxed poll (no per-iteration invalidate),
// single acquire-fence after. Weights live in LDS so the L1/L2 invalidates
// here cost nothing beyond the small per-step data refetch.
__device__ __forceinline__ void gbar(int* __restrict__ bar) {
  __builtin_amdgcn_fence(__ATOMIC_RELEASE, "agent");  // flush my global stores
  __syncthreads();
  if (threadIdx.x == 0) {
    int g0 = __hip_atomic_load(&bar[1], __ATOMIC_RELAXED, __HIP_MEMORY_SCOPE_AGENT);
    int v = __hip_atomic_fetch_add(&bar[0], 1, __ATOMIC_RELAXED, __HIP_MEMORY_SCOPE_AGENT);
    if (v == NWG_S - 1) {
      __hip_atomic_store(&bar[0], 0, __ATOMIC_RELAXED, __HIP_MEMORY_SCOPE_AGENT);
      __hip_atomic_store(&bar[1], g0 + 1, __ATOMIC_RELEASE, __HIP_MEMORY_SCOPE_AGENT);
    } else {
      while (__hip_atomic_load(&bar[1], __ATOMIC_RELAXED, __HIP_MEMORY_SCOPE_AGENT) == g0)
        __builtin_amdgcn_s_sleep(4);
    }
  }
  __syncthreads();
  __builtin_amdgcn_fence(__ATOMIC_ACQUIRE, "agent");  // invalidate L1 for fresh reads
}

// ============ serial chain: 128 steps, LDS-resident weight slices ==========
// e_t = exp(base_t + Wfc[:,1024:] @ relu( (fca_w @ e_{t-1})/S_{t-1} + fca_b ))
// d_out holds unnormalized e; Sp holds 16 partial sums per step; norm_k divides.
__global__ __launch_bounds__(256) void serial_k(
    const float* __restrict__ fca_w, const float* __restrict__ fca_b,
    const float* __restrict__ fc_w, const float* __restrict__ action,
    const float* __restrict__ base, float* __restrict__ a_buf,
    float* __restrict__ Sp, float* __restrict__ e_out, int* __restrict__ bar) {
  int g = blockIdx.x;   // 0..15
  int t = threadIdx.x;
  __shared__ float wa[AR * 400];   // fca_w rows [g*32, g*32+32)          51.2 KB
  __shared__ float wb[BR * 520];   // fc_w rows [g*25,+25), cols 1024.. , 52 KB (pad 512->520)
  __shared__ float sh_e[400];
  __shared__ float sh_a[512];
  __shared__ float sred[32];
  __shared__ float sS[16];

  // ---- one-time LDS weight staging (contiguous / coalesced) ----
  for (int i = t; i < AR * 400; i += 256) wa[i] = fca_w[g * AR * 400 + i];
  for (int i = t; i < BR * 512; i += 256) {
    int r = i >> 9, c = i & 511;
    wb[r * 520 + c] = fc_w[(g * BR + r) * 1536 + 1024 + c];
  }
  float fab = fca_b[g * AR + (t >> 3)];  // bias for my phase-A row

  const int row = t >> 3;       // 0..31
  const int p4 = (t & 7) * 4;   // col sub-offset

  for (int step = 0; step < 128; ++step) {
    // ---- stage e_{t-1} (global, cross-WG) and S partials into LDS ----
    const float* eprev = step ? (e_out + (step - 1) * 400) : action;
    for (int i = t; i < 400; i += 256) sh_e[i] = eprev[i];
    if (t < 16) sS[t] = step ? Sp[(step - 1) * 16 + t] : (1.f / 16.f);
    __syncthreads();
    float Ssum = 0.f;
#pragma unroll
    for (int i = 0; i < 16; ++i) Ssum += sS[i];
    float invS = 1.f / Ssum;

    {  // ---- phase A: a[g*32+row] = relu((wa[row,:].e)/S + b) ----
      const float* wrow = &wa[row * 400];
      float s = 0.f;
#pragma unroll
      for (int k = 0; k < 12; ++k) {
        f32x4 w = *(const f32x4*)&wrow[p4 + 32 * k];
        f32x4 x = *(const f32x4*)&sh_e[p4 + 32 * k];
        s += w.x * x.x + w.y * x.y + w.z * x.z + w.w * x.w;
      }
      if ((t & 7) < 4) {  // tail cols 384..399
        f32x4 w = *(const f32x4*)&wrow[384 + p4];
        f32x4 x = *(const f32x4*)&sh_e[384 + p4];
        s += w.x * x.x + w.y * x.y + w.z * x.z + w.w * x.w;
      }
      s += __shfl_xor(s, 1);
      s += __shfl_xor(s, 2);
      s += __shfl_xor(s, 4);
      if ((t & 7) == 0) a_buf[g * AR + row] = fmaxf(s * invS + fab, 0.f);
    }
    gbar(bar);

    // ---- stage a (512) ----
    for (int i = t; i < 512; i += 256) sh_a[i] = a_buf[i];
    __syncthreads();

    {  // ---- phase B: e[g*25+row] = exp(wb[row,:].a + base) ----
      if (row < BR) {
        const float* wrow = &wb[row * 520];
        float s = 0.f;
#pragma unroll
        for (int k = 0; k < 16; ++k) {
          f32x4 w = *(const f32x4*)&wrow[p4 + 32 * k];
          f32x4 x = *(const f32x4*)&sh_a[p4 + 32 * k];
          s += w.x * x.x + w.y * x.y + w.z * x.z + w.w * x.w;
        }
        s += __shfl_xor(s, 1);
        s += __shfl_xor(s, 2);
        s += __shfl_xor(s, 4);
        if ((t & 7) == 0) {
          int orow = g * BR + row;
          float e = __expf(s + base[step * 400 + orow]);
          e_out[step * 400 + orow] = e;
          sred[row] = e;
        }
      }
    }
    __syncthreads();
    if (t == 0) {
      float tot = 0.f;
#pragma unroll
      for (int i = 0; i < BR; ++i) tot += sred[i];
      Sp[step * 16 + g] = tot;
    }
    if (step == 127) break;  // no consumer inside the kernel after last step
    gbar(bar);
  }
}

// ================= final softmax normalization =============================
__global__ __launch_bounds__(256) void norm_k(float* __restrict__ out,
                                              const float* __restrict__ Sp) {
  int i = blockIdx.x * 256 + threadIdx.x;
  if (i < 51200) {
    const float* sp = Sp + (i / 400) * 16;
    float s = 0.f;
#pragma unroll
    for (int j = 0; j < 16; ++j) s += sp[j];
    out[i] = out[i] / s;
  }
}

extern "C" void kernel_launch(void* const* d_in, const int* in_sizes, int n_in,
                              void* d_out, int out_size, void* d_ws, size_t ws_size,
                              hipStream_t stream) {
  (void)in_sizes; (void)n_in; (void)out_size;
  const float* enc    = (const float*)d_in[0];
  const float* vid    = (const float*)d_in[1];
  const float* action = (const float*)d_in[2];
  const float* c1w    = (const float*)d_in[3];
  const float* c1b    = (const float*)d_in[4];
  const float* c2w    = (const float*)d_in[5];
  const float* c2b    = (const float*)d_in[6];
  const float* fce_w  = (const float*)d_in[7];
  const float* fce_b  = (const float*)d_in[8];
  const float* fca_w  = (const float*)d_in[9];
  const float* fca_b  = (const float*)d_in[10];
  const float* fc_w   = (const float*)d_in[11];
  const float* fc_b   = (const float*)d_in[12];
  // d_in[13..16] (wih/whh/bih/bhh): dead code — LSTM state never reaches the output.
  float* out = (float*)d_out;
  char* ws = (char*)d_ws;
  unsigned short* w2t = (unsigned short*)(ws + 0);
  float* feats_sum    = (float*)(ws + 147456);
  float* ev           = (float*)(ws + 212992);
  float* base         = (float*)(ws + 216576);
  float* a_buf        = (float*)(ws + 421376);
  float* Sp           = (float*)(ws + 423424);
  int*   bar          = (int*)(ws + 431616);
  unsigned short* c1  = (unsigned short*)(ws + 458752);

  // choose frame-chunk size to fit the workspace (c1 = fchunk * 2 MiB)
  int fchunk = 32;
  while (fchunk > 1 && 458752ull + (unsigned long long)fchunk * 2097152ull > ws_size)
    fchunk >>= 1;

  hipLaunchKernelGGL(prep_k, dim3(64), dim3(256), 0, stream,
                     enc, fce_w, fce_b, c2w, w2t, ev, feats_sum, bar);
  for (int fb = 0; fb < 128; fb += fchunk) {
    hipLaunchKernelGGL(conv1_k, dim3(fchunk * 64), dim3(256), 0, stream,
                       vid, c1w, c1b, c1, fb);
    hipLaunchKernelGGL(conv2_k, dim3(fchunk * 32), dim3(256), 0, stream,
                       c1, w2t, c2b, feats_sum, fb);
  }
  hipLaunchKernelGGL(base_k, dim3(128), dim3(256), 0, stream,
                     feats_sum, ev, fc_w, fc_b, base);
  hipLaunchKernelGGL(serial_k, dim3(NWG_S), dim3(256), 0, stream,
                     fca_w, fca_b, fc_w, action, base, a_buf, Sp, out, bar);
  hipLaunchKernelGGL(norm_k, dim3(200), dim3(256), 0, stream, out, Sp);
}

// Round 3
// 1565.479 us; speedup vs baseline: 3.7079x; 1.4885x over previous
//
#include <hip/hip_runtime.h>

typedef float f32x4 __attribute__((ext_vector_type(4)));
typedef short short8 __attribute__((ext_vector_type(8)));

#define NWG_S 16   // serial-chain worker workgroups
#define AR 32      // a-rows per WG (512/16)
#define OR 25      // output rows per WG (400/16)

__device__ __forceinline__ unsigned short f2bf(float f) {
  unsigned int u = __float_as_uint(f);
  u += 0x7fffu + ((u >> 16) & 1u);
  return (unsigned short)(u >> 16);
}

// ---------------- workspace layout (bytes) ----------------
// 0       : w2t       bf16[128][576]  transposed conv2 weights (147456)
// 147456  : feats_sum f32 [128][128]  (65536)   zeroed each launch
// 212992  : ev        f32 [896]       (3584)
// 216576  : base      f32 [128][400]  (204800)
// 421376  : pe        f32 [2][16][400] partial logits, ping-pong (51200)
// 472576  : seq       int [16]        per-WG step flags, zeroed each launch
// 524288  : c1        bf16[FCHUNK][128][128][64] (FCHUNK*2 MiB)

// ================= prep: zero accumulators, transpose conv2_w, fce branch ==
__global__ __launch_bounds__(256) void prep_k(
    const float* __restrict__ enc, const float* __restrict__ fce_w,
    const float* __restrict__ fce_b, const float* __restrict__ conv2_w,
    unsigned short* __restrict__ w2t, float* __restrict__ ev,
    float* __restrict__ feats_sum, int* __restrict__ seq) {
  int b = blockIdx.x, t = threadIdx.x;
  if (b < 48) {
    for (int i = b * 256 + t; i < 16400; i += 48 * 256) {
      if (i < 16384) feats_sum[i] = 0.f;
      else seq[i - 16384] = 0;
    }
    for (int i = b * 256 + t; i < 73728; i += 48 * 256) {
      int oc = i / 576, k = i - oc * 576;
      int p = k >> 6, ic = k & 63;
      int ky = p / 3, kx = p - ky * 3;
      w2t[i] = f2bf(conv2_w[((oc * 64 + ic) * 3 + ky) * 3 + kx]);
    }
  } else {
    // ev[n*64+o] = relu(enc[n,:] . fce_w[o,:] + fce_b[o]); 16 blocks x 56 outs
    if (t < 224) {
      int o_l = t >> 2, part = t & 3;
      int o_glob = (b - 48) * 56 + o_l;
      int n = o_glob >> 6, o = o_glob & 63;
      const f32x4* e4 = (const f32x4*)(enc + n * 2048);
      const f32x4* w4 = (const f32x4*)(fce_w + o * 2048);
      float s = 0.f;
      for (int d = part * 128; d < part * 128 + 128; ++d) {
        f32x4 a = e4[d], w = w4[d];
        s += a.x * w.x + a.y * w.y + a.z * w.z + a.w * w.w;
      }
      s += __shfl_xor(s, 1);
      s += __shfl_xor(s, 2);
      if (part == 0) ev[o_glob] = fmaxf(s + fce_b[o], 0.f);
    }
  }
}

// ================= conv1: f32 in -> relu -> bf16 NHWC out ==================
__global__ __launch_bounds__(256) void conv1_k(
    const float* __restrict__ vid, const float* __restrict__ cw,
    const float* __restrict__ cb, unsigned short* __restrict__ c1, int fbase) {
  int f_local = blockIdx.x >> 6;
  int pix = (blockIdx.x & 63) * 256 + threadIdx.x;  // 0..16383
  int oy = pix >> 7, ox = pix & 127;
  int f = fbase + f_local;
  float inv[27];
#pragma unroll
  for (int c = 0; c < 3; ++c)
#pragma unroll
    for (int ky = 0; ky < 3; ++ky)
#pragma unroll
      for (int kx = 0; kx < 3; ++kx) {
        int iy = 2 * oy - 1 + ky, ix = 2 * ox - 1 + kx;
        bool ok = (iy >= 0 && iy < 256 && ix >= 0 && ix < 256);
        inv[c * 9 + ky * 3 + kx] = ok ? vid[((f * 3 + c) * 256 + iy) * 256 + ix] : 0.f;
      }
  long obase = (long)((f_local * 128 + oy) * 128 + ox) * 64;
  for (int g = 0; g < 8; ++g) {  // oc in groups of 8, weights via uniform (scalar) loads
    unsigned short pack[8];
#pragma unroll
    for (int j = 0; j < 8; ++j) {
      int oc = g * 8 + j;
      float s = cb[oc];
#pragma unroll
      for (int i = 0; i < 27; ++i) s += cw[oc * 27 + i] * inv[i];
      pack[j] = f2bf(fmaxf(s, 0.f));
    }
    *(uint4*)&c1[obase + g * 8] = *(const uint4*)pack;
  }
}

// ============ conv2: MFMA implicit GEMM + relu + spatial-mean ==============
// M-tile 128 pixels/WG, N=128 oc, K=576 in 18 steps of 32.
__global__ __launch_bounds__(256) void conv2_k(
    const unsigned short* __restrict__ c1, const unsigned short* __restrict__ w2t,
    const float* __restrict__ c2b, float* __restrict__ feats_sum, int fbase) {
  __shared__ unsigned short As[128 * 40];  // [row][k] pad 32->40 (bank spread)
  __shared__ unsigned short Bs[128 * 40];  // [oc][k]  (B^T layout)
  __shared__ float fred[128];
  int t = threadIdx.x;
  int f_local = blockIdx.x >> 5, mb = blockIdx.x & 31;
  int wave = t >> 6, lane = t & 63;

  f32x4 acc0[8], acc1[8];
#pragma unroll
  for (int n = 0; n < 8; ++n) {
    acc0[n] = (f32x4){0.f, 0.f, 0.f, 0.f};
    acc1[n] = (f32x4){0.f, 0.f, 0.f, 0.f};
  }

  int r = t >> 1, seg = t & 1;          // staging: 2 threads/row, 16 bf16 each
  int m = mb * 128 + r;
  int oy = m >> 6, ox = m & 63;
  const int aoff = r * 40 + seg * 16;

  for (int kk = 0; kk < 18; ++kk) {
    int p = kk >> 1, ic0 = (kk & 1) * 32;
    int ky = p / 3, kx = p - ky * 3;
    int iy = 2 * oy - 1 + ky, ix = 2 * ox - 1 + kx;
    if (iy >= 0 && iy < 128 && ix >= 0 && ix < 128) {
      const unsigned short* src =
          &c1[(long)((f_local * 128 + iy) * 128 + ix) * 64 + ic0 + seg * 16];
      *(uint4*)&As[aoff] = *(const uint4*)&src[0];
      *(uint4*)&As[aoff + 8] = *(const uint4*)&src[8];
    } else {
      *(uint4*)&As[aoff] = make_uint4(0u, 0u, 0u, 0u);
      *(uint4*)&As[aoff + 8] = make_uint4(0u, 0u, 0u, 0u);
    }
    {
      const unsigned short* src = &w2t[r * 576 + p * 64 + ic0 + seg * 16];
      *(uint4*)&Bs[aoff] = *(const uint4*)&src[0];
      *(uint4*)&Bs[aoff + 8] = *(const uint4*)&src[8];
    }
    __syncthreads();
    short8 av0 = *(const short8*)&As[(wave * 32 + (lane & 15)) * 40 + (lane >> 4) * 8];
    short8 av1 = *(const short8*)&As[(wave * 32 + 16 + (lane & 15)) * 40 + (lane >> 4) * 8];
#pragma unroll
    for (int n = 0; n < 8; ++n) {
      short8 bv = *(const short8*)&Bs[(n * 16 + (lane & 15)) * 40 + (lane >> 4) * 8];
      acc0[n] = __builtin_amdgcn_mfma_f32_16x16x32_bf16(av0, bv, acc0[n], 0, 0, 0);
      acc1[n] = __builtin_amdgcn_mfma_f32_16x16x32_bf16(av1, bv, acc1[n], 0, 0, 0);
    }
    __syncthreads();
  }

  // epilogue: bias + relu + sum over this WG's 128 pixels, then one atomic/oc
  if (t < 128) fred[t] = 0.f;
  __syncthreads();
  int f = fbase + f_local;
  int colLane = lane & 15;
#pragma unroll
  for (int n = 0; n < 8; ++n) {
    float bias = c2b[n * 16 + colLane];
    float s = 0.f;
#pragma unroll
    for (int q = 0; q < 4; ++q)
      s += fmaxf(acc0[n][q] + bias, 0.f) + fmaxf(acc1[n][q] + bias, 0.f);
    s += __shfl_xor(s, 16);
    s += __shfl_xor(s, 32);
    if (lane < 16) atomicAdd(&fred[n * 16 + colLane], s);
  }
  __syncthreads();
  if (t < 128) atomicAdd(&feats_sum[f * 128 + t], fred[t]);
}

// ====== base[t][c] = feats_t.Wf + ev.We + fc_b (time-independent part) =====
__global__ __launch_bounds__(256) void base_k(
    const float* __restrict__ feats_sum, const float* __restrict__ ev,
    const float* __restrict__ fc_w, const float* __restrict__ fc_b,
    float* __restrict__ base) {
  __shared__ float xv[1024];
  int tfr = blockIdx.x, t = threadIdx.x;
  for (int i = t; i < 1024; i += 256)
    xv[i] = (i < 128) ? feats_sum[tfr * 128 + i] * (1.f / 4096.f) : ev[i - 128];
  __syncthreads();
  for (int c = t; c < 400; c += 256) {
    const float* wr = fc_w + c * 1536;
    float s = fc_b[c];
    for (int k = 0; k < 1024; k += 4) {
      f32x4 w4 = *(const f32x4*)&wr[k];
      s += w4.x * xv[k] + w4.y * xv[k + 1] + w4.z * xv[k + 2] + w4.w * xv[k + 3];
    }
    base[tfr * 400 + c] = s;
  }
}

// ============ serial chain: 128 steps, ONE partial-logit exchange per step =
// WG g owns a-rows [32g,32g+32) and output rows [25g,25g+25).
// Per step: a_own = relu(Wa_rows . p)        (p held locally in LDS)
//           pe_g[400] = WfcT[:, own cols] . a_own   -> global + flag
//           poll 16 flags -> gather partials -> logits=base+sum -> softmax
//           p (normalized!) recomputed locally by every WG; own 25 rows -> d_out
__global__ __launch_bounds__(256) void serial_k(
    const float* __restrict__ fca_w, const float* __restrict__ fca_b,
    const float* __restrict__ fc_w, const float* __restrict__ action,
    const float* __restrict__ base, float* __restrict__ pe,
    int* __restrict__ seq, float* __restrict__ out) {
  int g = blockIdx.x;   // 0..15
  int t = threadIdx.x;
  __shared__ float wa[AR * 400];    // fca_w rows [g*32,+32)             51.2 KB
  __shared__ float wb2[400 * 33];   // fc_w[:,1024+g*32 ..+32] pad 33    52.8 KB
  __shared__ float sh_p[400];       // current softmax vector (local copy)
  __shared__ float sh_a[AR];        // own a slice
  __shared__ float sred[4];

  // ---- one-time LDS weight staging ----
  for (int i = t; i < AR * 400; i += 256) wa[i] = fca_w[g * AR * 400 + i];
  for (int i = t; i < 400 * 32; i += 256) {
    int r = i >> 5, c = i & 31;
    wb2[r * 33 + c] = fc_w[r * 1536 + 1024 + g * AR + c];
  }
  for (int i = t; i < 400; i += 256) sh_p[i] = action[i];  // step-0 input (raw)
  float fab = fca_b[g * AR + (t >> 3)];
  const int row = t >> 3;       // 0..31
  const int p4 = (t & 7) * 4;
  const unsigned lo = g * OR;
  __syncthreads();

  for (int step = 0; step < 128; ++step) {
    {  // ---- phase A: sh_a[row] = relu(wa[row,:].sh_p + b) ----
      const float* wrow = &wa[row * 400];
      float s = 0.f;
#pragma unroll
      for (int k = 0; k < 12; ++k) {
        f32x4 w = *(const f32x4*)&wrow[p4 + 32 * k];
        f32x4 x = *(const f32x4*)&sh_p[p4 + 32 * k];
        s += w.x * x.x + w.y * x.y + w.z * x.z + w.w * x.w;
      }
      if ((t & 7) < 4) {  // tail cols 384..399
        f32x4 w = *(const f32x4*)&wrow[384 + p4];
        f32x4 x = *(const f32x4*)&sh_p[384 + p4];
        s += w.x * x.x + w.y * x.y + w.z * x.z + w.w * x.w;
      }
      s += __shfl_xor(s, 1);
      s += __shfl_xor(s, 2);
      s += __shfl_xor(s, 4);
      if ((t & 7) == 0) sh_a[row] = fmaxf(s + fab, 0.f);
    }
    // prefetch base row (immutable data; independent of the flag handshake)
    float breg0 = base[step * 400 + t];
    float breg1 = (t < 144) ? base[step * 400 + 256 + t] : 0.f;
    __syncthreads();

    // ---- partial logits: pe_g[c] = wb2[c,:].sh_a ----
    float* peb = pe + ((step & 1) * 16 + g) * 400;
    for (int c = t; c < 400; c += 256) {
      float s = 0.f;
#pragma unroll
      for (int j = 0; j < 32; ++j) s += wb2[c * 33 + j] * sh_a[j];
      peb[c] = s;
    }
    __builtin_amdgcn_fence(__ATOMIC_RELEASE, "agent");  // per-wave store drain + L2 wb
    __syncthreads();
    if (t == 0)
      __hip_atomic_store(&seq[g], step + 1, __ATOMIC_RELAXED, __HIP_MEMORY_SCOPE_AGENT);

    // ---- wait for all 16 partials ----
    if (t < 16) {
      while (__hip_atomic_load(&seq[t], __ATOMIC_RELAXED, __HIP_MEMORY_SCOPE_AGENT) <
             step + 1)
        __builtin_amdgcn_s_sleep(1);
    }
    __syncthreads();
    __builtin_amdgcn_fence(__ATOMIC_ACQUIRE, "agent");  // invalidate for fresh reads

    // ---- combine: logits = base + sum_h pe_h; softmax fully local ----
    const float* pebase = pe + (step & 1) * (16 * 400);
    float l0 = breg0, l1 = breg1;
#pragma unroll
    for (int h = 0; h < 16; ++h) l0 += pebase[h * 400 + t];
    float e0 = __expf(l0), e1 = 0.f;
    if (t < 144) {
#pragma unroll
      for (int h = 0; h < 16; ++h) l1 += pebase[h * 400 + 256 + t];
      e1 = __expf(l1);
    }
    float sp = e0 + e1;
    sp += __shfl_xor(sp, 1);
    sp += __shfl_xor(sp, 2);
    sp += __shfl_xor(sp, 4);
    sp += __shfl_xor(sp, 8);
    sp += __shfl_xor(sp, 16);
    sp += __shfl_xor(sp, 32);
    if ((t & 63) == 0) sred[t >> 6] = sp;
    __syncthreads();
    float S = sred[0] + sred[1] + sred[2] + sred[3];
    float q0 = e0 / S;
    sh_p[t] = q0;
    if ((unsigned)(t - lo) < (unsigned)OR) out[step * 400 + t] = q0;
    if (t < 144) {
      float q1 = e1 / S;
      sh_p[256 + t] = q1;
      if ((unsigned)(256 + t - lo) < (unsigned)OR) out[step * 400 + 256 + t] = q1;
    }
    __syncthreads();  // sh_p ready for next phase A (and sh_a reusable)
  }
}

extern "C" void kernel_launch(void* const* d_in, const int* in_sizes, int n_in,
                              void* d_out, int out_size, void* d_ws, size_t ws_size,
                              hipStream_t stream) {
  (void)in_sizes; (void)n_in; (void)out_size;
  const float* enc    = (const float*)d_in[0];
  const float* vid    = (const float*)d_in[1];
  const float* action = (const float*)d_in[2];
  const float* c1w    = (const float*)d_in[3];
  const float* c1b    = (const float*)d_in[4];
  const float* c2w    = (const float*)d_in[5];
  const float* c2b    = (const float*)d_in[6];
  const float* fce_w  = (const float*)d_in[7];
  const float* fce_b  = (const float*)d_in[8];
  const float* fca_w  = (const float*)d_in[9];
  const float* fca_b  = (const float*)d_in[10];
  const float* fc_w   = (const float*)d_in[11];
  const float* fc_b   = (const float*)d_in[12];
  // d_in[13..16] (wih/whh/bih/bhh): dead code — LSTM state never reaches the output.
  float* out = (float*)d_out;
  char* ws = (char*)d_ws;
  unsigned short* w2t = (unsigned short*)(ws + 0);
  float* feats_sum    = (float*)(ws + 147456);
  float* ev           = (float*)(ws + 212992);
  float* base         = (float*)(ws + 216576);
  float* pe           = (float*)(ws + 421376);
  int*   seq          = (int*)(ws + 472576);
  unsigned short* c1  = (unsigned short*)(ws + 524288);

  // choose frame-chunk size to fit the workspace (c1 = fchunk * 2 MiB)
  int fchunk = 32;
  while (fchunk > 1 && 524288ull + (unsigned long long)fchunk * 2097152ull > ws_size)
    fchunk >>= 1;

  hipLaunchKernelGGL(prep_k, dim3(64), dim3(256), 0, stream,
                     enc, fce_w, fce_b, c2w, w2t, ev, feats_sum, seq);
  for (int fb = 0; fb < 128; fb += fchunk) {
    hipLaunchKernelGGL(conv1_k, dim3(fchunk * 64), dim3(256), 0, stream,
                       vid, c1w, c1b, c1, fb);
    hipLaunchKernelGGL(conv2_k, dim3(fchunk * 32), dim3(256), 0, stream,
                       c1, w2t, c2b, feats_sum, fb);
  }
  hipLaunchKernelGGL(base_k, dim3(128), dim3(256), 0, stream,
                     feats_sum, ev, fc_w, fc_b, base);
  hipLaunchKernelGGL(serial_k, dim3(NWG_S), dim3(256), 0, stream,
                     fca_w, fca_b, fc_w, action, base, pe, seq, out);
}

// Round 4
// 1422.704 us; speedup vs baseline: 4.0800x; 1.1004x over previous
//
#include <hip/hip_runtime.h>

typedef float f32x4 __attribute__((ext_vector_type(4)));
typedef short short8 __attribute__((ext_vector_type(8)));

#define NWG_S 16   // serial-chain worker workgroups
#define AR 32      // a-rows per WG (512/16)
#define OR 25      // output rows per WG (400/16)

__device__ __forceinline__ unsigned short f2bf(float f) {
  unsigned int u = __float_as_uint(f);
  u += 0x7fffu + ((u >> 16) & 1u);
  return (unsigned short)(u >> 16);
}

// ---------------- workspace layout (bytes) ----------------
// 0       : w2t       bf16[128][576]  transposed conv2 weights (147456)
// 147456  : feats_sum f32 [128][128]  (65536)   zeroed each launch
// 212992  : ev        f32 [896]       (3584)
// 216576  : base      f32 [128][400]  (204800)
// 421376  : pe        f32 [2][16][400] partial logits, ping-pong (51200)
// 472576  : seq       int [16]        per-WG step flags, zeroed each launch
// 524288  : c1        bf16[FCHUNK][128][128][64] (FCHUNK*2 MiB)

// ================= prep: zero accumulators, transpose conv2_w, fce branch ==
__global__ __launch_bounds__(256) void prep_k(
    const float* __restrict__ enc, const float* __restrict__ fce_w,
    const float* __restrict__ fce_b, const float* __restrict__ conv2_w,
    unsigned short* __restrict__ w2t, float* __restrict__ ev,
    float* __restrict__ feats_sum, int* __restrict__ seq) {
  int b = blockIdx.x, t = threadIdx.x;
  if (b < 48) {
    for (int i = b * 256 + t; i < 16400; i += 48 * 256) {
      if (i < 16384) feats_sum[i] = 0.f;
      else seq[i - 16384] = 0;
    }
    for (int i = b * 256 + t; i < 73728; i += 48 * 256) {
      int oc = i / 576, k = i - oc * 576;
      int p = k >> 6, ic = k & 63;
      int ky = p / 3, kx = p - ky * 3;
      w2t[i] = f2bf(conv2_w[((oc * 64 + ic) * 3 + ky) * 3 + kx]);
    }
  } else {
    // ev[n*64+o] = relu(enc[n,:] . fce_w[o,:] + fce_b[o]); 16 blocks x 56 outs
    if (t < 224) {
      int o_l = t >> 2, part = t & 3;
      int o_glob = (b - 48) * 56 + o_l;
      int n = o_glob >> 6, o = o_glob & 63;
      const f32x4* e4 = (const f32x4*)(enc + n * 2048);
      const f32x4* w4 = (const f32x4*)(fce_w + o * 2048);
      float s = 0.f;
      for (int d = part * 128; d < part * 128 + 128; ++d) {
        f32x4 a = e4[d], w = w4[d];
        s += a.x * w.x + a.y * w.y + a.z * w.z + a.w * w.w;
      }
      s += __shfl_xor(s, 1);
      s += __shfl_xor(s, 2);
      if (part == 0) ev[o_glob] = fmaxf(s + fce_b[o], 0.f);
    }
  }
}

// ================= conv1: f32 in -> relu -> bf16 NHWC out ==================
__global__ __launch_bounds__(256) void conv1_k(
    const float* __restrict__ vid, const float* __restrict__ cw,
    const float* __restrict__ cb, unsigned short* __restrict__ c1, int fbase) {
  int f_local = blockIdx.x >> 6;
  int pix = (blockIdx.x & 63) * 256 + threadIdx.x;  // 0..16383
  int oy = pix >> 7, ox = pix & 127;
  int f = fbase + f_local;
  float inv[27];
#pragma unroll
  for (int c = 0; c < 3; ++c)
#pragma unroll
    for (int ky = 0; ky < 3; ++ky)
#pragma unroll
      for (int kx = 0; kx < 3; ++kx) {
        int iy = 2 * oy - 1 + ky, ix = 2 * ox - 1 + kx;
        bool ok = (iy >= 0 && iy < 256 && ix >= 0 && ix < 256);
        inv[c * 9 + ky * 3 + kx] = ok ? vid[((f * 3 + c) * 256 + iy) * 256 + ix] : 0.f;
      }
  long obase = (long)((f_local * 128 + oy) * 128 + ox) * 64;
  for (int g = 0; g < 8; ++g) {  // oc in groups of 8, weights via uniform (scalar) loads
    unsigned short pack[8];
#pragma unroll
    for (int j = 0; j < 8; ++j) {
      int oc = g * 8 + j;
      float s = cb[oc];
#pragma unroll
      for (int i = 0; i < 27; ++i) s += cw[oc * 27 + i] * inv[i];
      pack[j] = f2bf(fmaxf(s, 0.f));
    }
    *(uint4*)&c1[obase + g * 8] = *(const uint4*)pack;
  }
}

// ============ conv2: MFMA implicit GEMM + relu + spatial-mean ==============
// M-tile 128 pixels/WG, N=128 oc, K=576 in 18 steps of 32.
__global__ __launch_bounds__(256) void conv2_k(
    const unsigned short* __restrict__ c1, const unsigned short* __restrict__ w2t,
    const float* __restrict__ c2b, float* __restrict__ feats_sum, int fbase) {
  __shared__ unsigned short As[128 * 40];  // [row][k] pad 32->40 (bank spread)
  __shared__ unsigned short Bs[128 * 40];  // [oc][k]  (B^T layout)
  __shared__ float fred[128];
  int t = threadIdx.x;
  int f_local = blockIdx.x >> 5, mb = blockIdx.x & 31;
  int wave = t >> 6, lane = t & 63;

  f32x4 acc0[8], acc1[8];
#pragma unroll
  for (int n = 0; n < 8; ++n) {
    acc0[n] = (f32x4){0.f, 0.f, 0.f, 0.f};
    acc1[n] = (f32x4){0.f, 0.f, 0.f, 0.f};
  }

  int r = t >> 1, seg = t & 1;          // staging: 2 threads/row, 16 bf16 each
  int m = mb * 128 + r;
  int oy = m >> 6, ox = m & 63;
  const int aoff = r * 40 + seg * 16;

  for (int kk = 0; kk < 18; ++kk) {
    int p = kk >> 1, ic0 = (kk & 1) * 32;
    int ky = p / 3, kx = p - ky * 3;
    int iy = 2 * oy - 1 + ky, ix = 2 * ox - 1 + kx;
    if (iy >= 0 && iy < 128 && ix >= 0 && ix < 128) {
      const unsigned short* src =
          &c1[(long)((f_local * 128 + iy) * 128 + ix) * 64 + ic0 + seg * 16];
      *(uint4*)&As[aoff] = *(const uint4*)&src[0];
      *(uint4*)&As[aoff + 8] = *(const uint4*)&src[8];
    } else {
      *(uint4*)&As[aoff] = make_uint4(0u, 0u, 0u, 0u);
      *(uint4*)&As[aoff + 8] = make_uint4(0u, 0u, 0u, 0u);
    }
    {
      const unsigned short* src = &w2t[r * 576 + p * 64 + ic0 + seg * 16];
      *(uint4*)&Bs[aoff] = *(const uint4*)&src[0];
      *(uint4*)&Bs[aoff + 8] = *(const uint4*)&src[8];
    }
    __syncthreads();
    short8 av0 = *(const short8*)&As[(wave * 32 + (lane & 15)) * 40 + (lane >> 4) * 8];
    short8 av1 = *(const short8*)&As[(wave * 32 + 16 + (lane & 15)) * 40 + (lane >> 4) * 8];
#pragma unroll
    for (int n = 0; n < 8; ++n) {
      short8 bv = *(const short8*)&Bs[(n * 16 + (lane & 15)) * 40 + (lane >> 4) * 8];
      acc0[n] = __builtin_amdgcn_mfma_f32_16x16x32_bf16(av0, bv, acc0[n], 0, 0, 0);
      acc1[n] = __builtin_amdgcn_mfma_f32_16x16x32_bf16(av1, bv, acc1[n], 0, 0, 0);
    }
    __syncthreads();
  }

  // epilogue: bias + relu + sum over this WG's 128 pixels, then one atomic/oc
  if (t < 128) fred[t] = 0.f;
  __syncthreads();
  int f = fbase + f_local;
  int colLane = lane & 15;
#pragma unroll
  for (int n = 0; n < 8; ++n) {
    float bias = c2b[n * 16 + colLane];
    float s = 0.f;
#pragma unroll
    for (int q = 0; q < 4; ++q)
      s += fmaxf(acc0[n][q] + bias, 0.f) + fmaxf(acc1[n][q] + bias, 0.f);
    s += __shfl_xor(s, 16);
    s += __shfl_xor(s, 32);
    if (lane < 16) atomicAdd(&fred[n * 16 + colLane], s);
  }
  __syncthreads();
  if (t < 128) atomicAdd(&feats_sum[f * 128 + t], fred[t]);
}

// ====== base[t][c] = feats_t.Wf + ev.We + fc_b (time-independent part) =====
__global__ __launch_bounds__(256) void base_k(
    const float* __restrict__ feats_sum, const float* __restrict__ ev,
    const float* __restrict__ fc_w, const float* __restrict__ fc_b,
    float* __restrict__ base) {
  __shared__ float xv[1024];
  int tfr = blockIdx.x, t = threadIdx.x;
  for (int i = t; i < 1024; i += 256)
    xv[i] = (i < 128) ? feats_sum[tfr * 128 + i] * (1.f / 4096.f) : ev[i - 128];
  __syncthreads();
  for (int c = t; c < 400; c += 256) {
    const float* wr = fc_w + c * 1536;
    float s = fc_b[c];
    for (int k = 0; k < 1024; k += 4) {
      f32x4 w4 = *(const f32x4*)&wr[k];
      s += w4.x * xv[k] + w4.y * xv[k + 1] + w4.z * xv[k + 2] + w4.w * xv[k + 3];
    }
    base[tfr * 400 + c] = s;
  }
}

// ============ serial chain: 128 steps, ONE partial-logit exchange per step =
// Cross-WG data is published WRITE-THROUGH to the coherence point (sc0/sc1 via
// agent-scope relaxed atomic stores) so NO buffer_wbl2 (release fence) is ever
// executed in the loop. Readers poll flags, then one cheap acquire-invalidate
// and gather the fresh partials from L3 with normal vectorizable loads.
__global__ __launch_bounds__(256) void serial_k(
    const float* __restrict__ fca_w, const float* __restrict__ fca_b,
    const float* __restrict__ fc_w, const float* __restrict__ action,
    const float* __restrict__ base, float* __restrict__ pe,
    int* __restrict__ seq, float* __restrict__ out) {
  int g = blockIdx.x;   // 0..15
  int t = threadIdx.x;
  __shared__ float wa[AR * 400];    // fca_w rows [g*32,+32)             51.2 KB
  __shared__ float wb2[400 * 33];   // fc_w[:,1024+g*32 ..+32] pad 33    52.8 KB
  __shared__ float sh_p[400];       // current softmax vector (local copy)
  __shared__ float sh_a[AR];        // own a slice
  __shared__ float sred[4];

  // ---- one-time LDS weight staging ----
  for (int i = t; i < AR * 400; i += 256) wa[i] = fca_w[g * AR * 400 + i];
  for (int i = t; i < 400 * 32; i += 256) {
    int r = i >> 5, c = i & 31;
    wb2[r * 33 + c] = fc_w[r * 1536 + 1024 + g * AR + c];
  }
  for (int i = t; i < 400; i += 256) sh_p[i] = action[i];  // step-0 input (raw)
  float fab = fca_b[g * AR + (t >> 3)];
  const int row = t >> 3;       // 0..31
  const int p4 = (t & 7) * 4;
  const unsigned lo = g * OR;
  __syncthreads();

  for (int step = 0; step < 128; ++step) {
    {  // ---- phase A: sh_a[row] = relu(wa[row,:].sh_p + b) ----
      const float* wrow = &wa[row * 400];
      float s = 0.f;
#pragma unroll
      for (int k = 0; k < 12; ++k) {
        f32x4 w = *(const f32x4*)&wrow[p4 + 32 * k];
        f32x4 x = *(const f32x4*)&sh_p[p4 + 32 * k];
        s += w.x * x.x + w.y * x.y + w.z * x.z + w.w * x.w;
      }
      if ((t & 7) < 4) {  // tail cols 384..399
        f32x4 w = *(const f32x4*)&wrow[384 + p4];
        f32x4 x = *(const f32x4*)&sh_p[384 + p4];
        s += w.x * x.x + w.y * x.y + w.z * x.z + w.w * x.w;
      }
      s += __shfl_xor(s, 1);
      s += __shfl_xor(s, 2);
      s += __shfl_xor(s, 4);
      if ((t & 7) == 0) sh_a[row] = fmaxf(s + fab, 0.f);
    }
    // prefetch base row (immutable, cached; hidden under phase A)
    float breg0 = base[step * 400 + t];
    float breg1 = (t < 144) ? base[step * 400 + 256 + t] : 0.f;
    __syncthreads();

    // ---- partial logits published write-through (sc0/sc1, no L2 dirty) ----
    float* peb = pe + ((step & 1) * 16 + g) * 400;
    for (int c = t; c < 400; c += 256) {
      float s = 0.f;
#pragma unroll
      for (int j = 0; j < 32; ++j) s += wb2[c * 33 + j] * sh_a[j];
      __hip_atomic_store(&peb[c], s, __ATOMIC_RELAXED, __HIP_MEMORY_SCOPE_AGENT);
    }
    asm volatile("s_waitcnt vmcnt(0)" ::: "memory");  // per-wave drain to coherence point
    __syncthreads();                                   // all waves drained
    if (t == 0)
      __hip_atomic_store(&seq[g], step + 1, __ATOMIC_RELAXED, __HIP_MEMORY_SCOPE_AGENT);

    // ---- wait for all 16 partials ----
    if (t < 16) {
      while (__hip_atomic_load(&seq[t], __ATOMIC_RELAXED, __HIP_MEMORY_SCOPE_AGENT) <
             step + 1)
        __builtin_amdgcn_s_sleep(1);
    }
    __syncthreads();
    __builtin_amdgcn_fence(__ATOMIC_ACQUIRE, "agent");  // flash-inv L1/L2 (no writeback)

    // ---- combine: logits = base + sum_h pe_h; softmax fully local ----
    const float* pebase = pe + (step & 1) * (16 * 400);
    float l0 = breg0, l1 = breg1;
#pragma unroll
    for (int h = 0; h < 16; ++h) l0 += pebase[h * 400 + t];
    float e0 = __expf(l0), e1 = 0.f;
    if (t < 144) {
#pragma unroll
      for (int h = 0; h < 16; ++h) l1 += pebase[h * 400 + 256 + t];
      e1 = __expf(l1);
    }
    float sp = e0 + e1;
    sp += __shfl_xor(sp, 1);
    sp += __shfl_xor(sp, 2);
    sp += __shfl_xor(sp, 4);
    sp += __shfl_xor(sp, 8);
    sp += __shfl_xor(sp, 16);
    sp += __shfl_xor(sp, 32);
    if ((t & 63) == 0) sred[t >> 6] = sp;
    __syncthreads();
    float S = sred[0] + sred[1] + sred[2] + sred[3];
    float q0 = e0 / S;
    sh_p[t] = q0;
    if ((unsigned)(t - lo) < (unsigned)OR) out[step * 400 + t] = q0;
    if (t < 144) {
      float q1 = e1 / S;
      sh_p[256 + t] = q1;
      if ((unsigned)(256 + t - lo) < (unsigned)OR) out[step * 400 + 256 + t] = q1;
    }
    __syncthreads();  // sh_p ready for next phase A (and sh_a reusable)
  }
}

extern "C" void kernel_launch(void* const* d_in, const int* in_sizes, int n_in,
                              void* d_out, int out_size, void* d_ws, size_t ws_size,
                              hipStream_t stream) {
  (void)in_sizes; (void)n_in; (void)out_size;
  const float* enc    = (const float*)d_in[0];
  const float* vid    = (const float*)d_in[1];
  const float* action = (const float*)d_in[2];
  const float* c1w    = (const float*)d_in[3];
  const float* c1b    = (const float*)d_in[4];
  const float* c2w    = (const float*)d_in[5];
  const float* c2b    = (const float*)d_in[6];
  const float* fce_w  = (const float*)d_in[7];
  const float* fce_b  = (const float*)d_in[8];
  const float* fca_w  = (const float*)d_in[9];
  const float* fca_b  = (const float*)d_in[10];
  const float* fc_w   = (const float*)d_in[11];
  const float* fc_b   = (const float*)d_in[12];
  // d_in[13..16] (wih/whh/bih/bhh): dead code — LSTM state never reaches the output.
  float* out = (float*)d_out;
  char* ws = (char*)d_ws;
  unsigned short* w2t = (unsigned short*)(ws + 0);
  float* feats_sum    = (float*)(ws + 147456);
  float* ev           = (float*)(ws + 212992);
  float* base         = (float*)(ws + 216576);
  float* pe           = (float*)(ws + 421376);
  int*   seq          = (int*)(ws + 472576);
  unsigned short* c1  = (unsigned short*)(ws + 524288);

  // choose frame-chunk size to fit the workspace (c1 = fchunk * 2 MiB)
  int fchunk = 32;
  while (fchunk > 1 && 524288ull + (unsigned long long)fchunk * 2097152ull > ws_size)
    fchunk >>= 1;

  hipLaunchKernelGGL(prep_k, dim3(64), dim3(256), 0, stream,
                     enc, fce_w, fce_b, c2w, w2t, ev, feats_sum, seq);
  for (int fb = 0; fb < 128; fb += fchunk) {
    hipLaunchKernelGGL(conv1_k, dim3(fchunk * 64), dim3(256), 0, stream,
                       vid, c1w, c1b, c1, fb);
    hipLaunchKernelGGL(conv2_k, dim3(fchunk * 32), dim3(256), 0, stream,
                       c1, w2t, c2b, feats_sum, fb);
  }
  hipLaunchKernelGGL(base_k, dim3(128), dim3(256), 0, stream,
                     feats_sum, ev, fc_w, fc_b, base);
  hipLaunchKernelGGL(serial_k, dim3(NWG_S), dim3(256), 0, stream,
                     fca_w, fca_b, fc_w, action, base, pe, seq, out);
}